// Round 3
// baseline (2578276.953 us; speedup 1.0000x reference)
//
#include <hip/hip_runtime.h>
#include <stdint.h>

#define NB 256  // persistent blocks == CUs
typedef unsigned long long u64;
typedef unsigned uint4v __attribute__((ext_vector_type(4)));
typedef float f32x4 __attribute__((ext_vector_type(4)));

// ---------- fast math ----------
__device__ __forceinline__ float sigm(float x) {
    return 1.f / (1.f + __expf(-x));
}
__device__ __forceinline__ float tanh_fast(float x) {
    // 1 - 2/(e^{2x}+1): monotone, correct limits at +-inf
    return 1.f - 2.f / (__expf(2.f * x) + 1.f);
}

// ---------- global (IF$) message words: {tag(hi32) | f32 payload(lo32)} ----------
__device__ __forceinline__ void astore(u64* p, u64 v) {
    __hip_atomic_store(p, v, __ATOMIC_RELAXED, __HIP_MEMORY_SCOPE_AGENT);
}

// Poll 4 consecutive message words with two 16B IF$-coherent loads (sc0 sc1).
// Each 8B word is individually tagged, so 16B tearing is harmless.
__device__ __forceinline__ f32x4 poll4v(const u64* m, unsigned tag) {
    uint4v x, y;
    for (;;) {
        asm volatile(
            "global_load_dwordx4 %0, %2, off sc0 sc1\n\t"
            "global_load_dwordx4 %1, %3, off sc0 sc1\n\t"
            "s_waitcnt vmcnt(0)"
            : "=&v"(x), "=&v"(y)
            : "v"(m), "v"(m + 2)
            : "memory");
        if (x.y == tag && x.w == tag && y.y == tag && y.w == tag) break;
        __builtin_amdgcn_s_sleep(1);
    }
    f32x4 r;
    r.x = __uint_as_float(x.x);
    r.y = __uint_as_float(x.z);
    r.z = __uint_as_float(y.x);
    r.w = __uint_as_float(y.z);
    return r;
}

// ---------- XCD-local (shared per-XCD L2) accesses: sc0 = bypass L1, hit L2 ----------
__device__ __forceinline__ unsigned ld_b32_l2(const unsigned* p) {
    unsigned v;
    asm volatile("global_load_dword %0, %1, off sc0\n\ts_waitcnt vmcnt(0)"
                 : "=v"(v)
                 : "v"(p)
                 : "memory");
    return v;
}
__device__ __forceinline__ f32x4 ld_b128_l2(const float* p) {
    f32x4 v;
    asm volatile("global_load_dwordx4 %0, %1, off sc0\n\ts_waitcnt vmcnt(0)"
                 : "=v"(v)
                 : "v"(p)
                 : "memory");
    return v;
}
__device__ __forceinline__ void st_b32_l2(unsigned* p, unsigned v) {
    // default store: write-back, allocates in this XCD's L2 (consumers sc0-read it)
    asm volatile("global_store_dword %0, %1, off" ::"v"(p), "v"(v) : "memory");
}

// ---------- kernel G: Gx[t][j] = emb[idx[t]] . W_ih[j] + b_ih[j] + b_hh[j] ----------
template <int TT>
__global__ __launch_bounds__(256) void gates_x_gemm(
    const int* __restrict__ idx, const float* __restrict__ emb,
    const float* __restrict__ Wih, const float* __restrict__ bih,
    const float* __restrict__ bhh, float* __restrict__ Gx) {
    __shared__ float As[TT][36];
    __shared__ float Ws[32][68];  // [k][j], padded
    const int tid = threadIdx.x;
    const int jt = blockIdx.x * 64;
    const int t0 = blockIdx.y * TT;
    constexpr int TPT = TT / 16;
    const int tx = tid & 15, ty = tid >> 4;
    float acc[TPT][4];
#pragma unroll
    for (int a = 0; a < TPT; ++a)
#pragma unroll
        for (int q = 0; q < 4; ++q) acc[a][q] = 0.f;

    for (int k0 = 0; k0 < 1024; k0 += 32) {
        if constexpr (TT == 32) {
            int t = tid >> 3, kq = (tid & 7) * 4;
            int row = idx[t0 + t];
            float4 v = *(const float4*)(emb + (size_t)row * 1024 + k0 + kq);
            *(float4*)&As[t][kq] = v;
        } else {
            int t = tid >> 4, kq = (tid & 15) * 2;
            int row = idx[t0 + t];
            float2 v = *(const float2*)(emb + (size_t)row * 1024 + k0 + kq);
            *(float2*)&As[t][kq] = v;
        }
        {
            int j = tid >> 3, kq = (tid & 7) * 4;
            float4 w0 = *(const float4*)(Wih + (size_t)(jt + j) * 1024 + k0 + kq);
            float4 w1 = *(const float4*)(Wih + (size_t)(jt + j + 32) * 1024 + k0 + kq);
            const float* p0 = (const float*)&w0;
            const float* p1 = (const float*)&w1;
#pragma unroll
            for (int c = 0; c < 4; ++c) {
                Ws[kq + c][j] = p0[c];
                Ws[kq + c][j + 32] = p1[c];
            }
        }
        __syncthreads();
#pragma unroll
        for (int kk = 0; kk < 32; kk += 4) {
            float4 av[TPT];
#pragma unroll
            for (int tt = 0; tt < TPT; ++tt)
                av[tt] = *(float4*)&As[ty * TPT + tt][kk];
#pragma unroll
            for (int c = 0; c < 4; ++c) {
                float4 wv = *(float4*)&Ws[kk + c][tx * 4];
#pragma unroll
                for (int tt = 0; tt < TPT; ++tt) {
                    const float* ap = (const float*)&av[tt];
                    float a = ap[c];
                    acc[tt][0] += a * wv.x;
                    acc[tt][1] += a * wv.y;
                    acc[tt][2] += a * wv.z;
                    acc[tt][3] += a * wv.w;
                }
            }
        }
        __syncthreads();
    }
    int j = jt + tx * 4;
    float4 bi = *(const float4*)(bih + j);
    float4 bh = *(const float4*)(bhh + j);
#pragma unroll
    for (int tt = 0; tt < TPT; ++tt) {
        int t = t0 + ty * TPT + tt;
        float4 r;
        r.x = acc[tt][0] + bi.x + bh.x;
        r.y = acc[tt][1] + bi.y + bh.y;
        r.z = acc[tt][2] + bi.z + bh.z;
        r.w = acc[tt][3] + bi.w + bh.w;
        *(float4*)(Gx + (size_t)t * 8192 + j) = r;
    }
}

// ---------- kernel P: persistent LSTM scans + MLP head ----------
// 256 blocks x 512 threads; block b owns h indices [b*8, b*8+8); wave w owns
// all 4 gate rows of h index b*8+w (W_hh slice in 128 VGPRs; butterfly gives
// every lane the full sums; gates computed redundantly; lane 0 publishes).
//
// Inter-block h broadcast is a 2-level tree matching the chiplet topology:
//   level 0 (IF$): producers publish tagged words; ONE hub block per XCD
//     polls them (8 pollers instead of 256 -> 30x fewer coherent-point reqs).
//   level 1 (XCD L2): hub re-stores the 8KB h vector + a flag into XCD-local
//     staging (default stores stay dirty in the shared per-XCD L2); the other
//     31 blocks poll the flag and bulk-read staging with sc0 loads (~150cy).
__global__ __launch_bounds__(512, 2) void lstm_mlp_persistent(
    const float* __restrict__ Whh_t, const float* __restrict__ Whh_a,
    const float* __restrict__ Gxt, const float* __restrict__ Gxa,
    const float* __restrict__ W1, const float* __restrict__ b1,
    const float* __restrict__ W2, const float* __restrict__ b2,
    const float* __restrict__ W3, const float* __restrict__ b3,
    u64* msg_t, u64* msg_a, unsigned* claim, unsigned* flags, float* stage,
    float* out) {
    // 84 KB pad forces 1 block/CU so all 256 blocks are co-resident (spin
    // safety); only the first 4096 floats are used (h double-buffer / MLP).
    __shared__ float h_lds[21504];
    __shared__ unsigned s_xcd, s_hub;
    const int tid = threadIdx.x;
    const int b = blockIdx.x;
    const int w = tid >> 6, l = tid & 63;

    // ---- hub election: one relay block per physical XCD ----
    if (tid == 0) {
        unsigned xc;
        asm volatile("s_getreg_b32 %0, hwreg(HW_REG_XCC_ID)" : "=s"(xc));
        xc &= 7;
        s_xcd = xc;
        s_hub = (atomicAdd(&claim[xc], 1u) == 0u) ? 1u : 0u;
    }
    __syncthreads();
    const unsigned xcd = s_xcd;
    const bool ishub = (s_hub != 0);
    unsigned* flagbase = flags + xcd * 64;           // 256B-padded: no false sharing
    float* stagebase = stage + (size_t)xcd * 4096;   // [2][2048] f32 per XCD

    for (int scan = 0; scan < 2; ++scan) {
        const float* Whh = scan ? Whh_a : Whh_t;
        const float* Gx = scan ? Gxa : Gxt;
        u64* msg = scan ? msg_a : msg_t;
        const int T = scan ? 16 : 128;
        const unsigned epbase = scan ? 128u : 0u;  // continuous epoch for flags

        float4 wreg[4][8];
#pragma unroll
        for (int q = 0; q < 4; ++q) {
            const int j = q * 2048 + b * 8 + w;
            const float* wrow = Whh + (size_t)j * 2048 + l * 4;
#pragma unroll
            for (int k8 = 0; k8 < 8; ++k8)
                wreg[q][k8] = *(const float4*)(wrow + k8 * 256);
        }
        float c = 0.f;  // cell state, replicated across the wave's lanes

        for (int t = 0; t < T; ++t) {
            // x-gates for this wave's h index: wave-uniform loads, issued
            // before the wait so their latency hides under it
            float gxv[4];
#pragma unroll
            for (int q = 0; q < 4; ++q)
                gxv[q] = Gx[(size_t)t * 8192 + q * 2048 + b * 8 + w];
            float* hstage = h_lds + (t & 1) * 2048;  // LDS double buffer
            if (t == 0) {
                *(f32x4*)(hstage + tid * 4) = f32x4{0.f, 0.f, 0.f, 0.f};
                __syncthreads();
            } else if (ishub) {
                // level 0: collect h[t] from IF$ (only 8 blocks do this)
                f32x4 pv = poll4v(msg + (t & 1) * 2048 + tid * 4, (unsigned)t);
                float* sg = stagebase + (t & 1) * 2048;
                *(f32x4*)(sg + tid * 4) = pv;       // XCD-local staging (L2)
                *(f32x4*)(hstage + tid * 4) = pv;   // own LDS copy
                asm volatile("s_waitcnt vmcnt(0)" ::: "memory");  // staging ack'd in L2
                __syncthreads();
                if (tid == 0) st_b32_l2(flagbase + (t & 1), epbase + (unsigned)t);
            } else {
                // level 1: wait on local-L2 flag (one line, wave-coalesced)
                const unsigned ep = epbase + (unsigned)t;
                const unsigned* fp = flagbase + (t & 1);
                int spins = 0;
                bool ok = true;
                while (ld_b32_l2(fp) != ep) {
                    __builtin_amdgcn_s_sleep(1);
                    if (++spins > 200000) {  // safety: fall back to IF$ poll
                        ok = false;
                        break;
                    }
                }
                f32x4 v;
                if (ok)
                    v = ld_b128_l2(stagebase + (t & 1) * 2048 + tid * 4);
                else
                    v = poll4v(msg + (t & 1) * 2048 + tid * 4, (unsigned)t);
                *(f32x4*)(hstage + tid * 4) = v;
                __syncthreads();
            }
            float4 hreg[8];
#pragma unroll
            for (int k8 = 0; k8 < 8; ++k8)
                hreg[k8] = *(float4*)(hstage + k8 * 256 + l * 4);
            float acc[4];
#pragma unroll
            for (int q = 0; q < 4; ++q) {
                float a = 0.f;
#pragma unroll
                for (int k8 = 0; k8 < 8; ++k8) {
                    a += wreg[q][k8].x * hreg[k8].x;
                    a += wreg[q][k8].y * hreg[k8].y;
                    a += wreg[q][k8].z * hreg[k8].z;
                    a += wreg[q][k8].w * hreg[k8].w;
                }
                acc[q] = a;
            }
#pragma unroll
            for (int q = 0; q < 4; ++q) {  // butterfly: total lands in ALL lanes
                float a = acc[q];
#pragma unroll
                for (int off = 32; off; off >>= 1) a += __shfl_xor(a, off, 64);
                acc[q] = a;
            }
            // gates, redundantly in every lane (deterministic => consistent)
            float gi = sigm(acc[0] + gxv[0]);
            float gf = sigm(acc[1] + gxv[1]);
            float gg = tanh_fast(acc[2] + gxv[2]);
            float go = sigm(acc[3] + gxv[3]);
            c = gf * c + gi * gg;
            float hval = go * tanh_fast(c);
            if (l == 0)  // publish h[t+1] to the IF$ message buffer
                astore(msg + ((t + 1) & 1) * 2048 + b * 8 + w,
                       ((u64)(unsigned)(t + 1) << 32) | (u64)__float_as_uint(hval));
        }
    }

    // ---- MLP head: summary = [h_title(2048), h_authors(2048)] ----
    // Only 3 sync points remain; use the direct IF$ protocol (simple, rare).
    {
        f32x4 v = poll4v(msg_t + tid * 4, 128u);  // title final h: tag 128, buf 0
        *(f32x4*)(h_lds + tid * 4) = v;
        v = poll4v(msg_a + tid * 4, 16u);  // authors final h: tag 16, buf 0
        *(f32x4*)(h_lds + 2048 + tid * 4) = v;
    }
    __syncthreads();
    {  // h1 = relu(W1 . summary + b1): row j per wave; publish as tag 129
        const int j = b * 8 + w;
        const float* wr = W1 + (size_t)j * 4096;
        float acc = 0.f;
#pragma unroll
        for (int i = 0; i < 16; ++i) {
            float4 wv = *(const float4*)(wr + i * 256 + l * 4);
            float4 hv = *(const float4*)(h_lds + i * 256 + l * 4);
            acc += wv.x * hv.x + wv.y * hv.y + wv.z * hv.z + wv.w * hv.w;
        }
#pragma unroll
        for (int off = 32; off; off >>= 1) acc += __shfl_xor(acc, off, 64);
        if (l == 0) {
            float h1 = fmaxf(acc + b1[j], 0.f);
            astore(msg_t + 2048 + j, (129ull << 32) | (u64)__float_as_uint(h1));
        }
    }
    __syncthreads();  // all summary reads done before h_lds overwrite
    {
        f32x4 v = poll4v(msg_t + 2048 + tid * 4, 129u);
        *(f32x4*)(h_lds + tid * 4) = v;
    }
    __syncthreads();
    {  // h2 = relu(W2 . h1 + b2): publish as tag 130
        const int j = b * 8 + w;
        const float* wr = W2 + (size_t)j * 2048;
        float acc = 0.f;
#pragma unroll
        for (int i = 0; i < 8; ++i) {
            float4 wv = *(const float4*)(wr + i * 256 + l * 4);
            float4 hv = *(const float4*)(h_lds + i * 256 + l * 4);
            acc += wv.x * hv.x + wv.y * hv.y + wv.z * hv.z + wv.w * hv.w;
        }
#pragma unroll
        for (int off = 32; off; off >>= 1) acc += __shfl_xor(acc, off, 64);
        if (l == 0) {
            float h2 = fmaxf(acc + b2[j], 0.f);
            astore(msg_t + j, (130ull << 32) | (u64)__float_as_uint(h2));
        }
    }
    if (b == 0) {  // logits: only block 0 consumes h2
        __syncthreads();  // h1 reads done before h_lds overwrite
        {
            f32x4 v = poll4v(msg_t + tid * 4, 130u);
            *(f32x4*)(h_lds + tid * 4) = v;
        }
        __syncthreads();
        if (w < 2) {
            const float* wr = W3 + (size_t)w * 2048;
            float acc = 0.f;
#pragma unroll
            for (int i = 0; i < 8; ++i) {
                float4 wv = *(const float4*)(wr + i * 256 + l * 4);
                float4 hv = *(const float4*)(h_lds + i * 256 + l * 4);
                acc += wv.x * hv.x + wv.y * hv.y + wv.z * hv.z + wv.w * hv.w;
            }
#pragma unroll
            for (int off = 32; off; off >>= 1) acc += __shfl_xor(acc, off, 64);
            if (l == 0) out[w] = acc + b3[w];
        }
    }
}

extern "C" void kernel_launch(void* const* d_in, const int* in_sizes, int n_in,
                              void* d_out, int out_size, void* d_ws,
                              size_t ws_size, hipStream_t stream) {
    const int* x_t = (const int*)d_in[0];
    const int* x_a = (const int*)d_in[1];
    const float* emb_t = (const float*)d_in[2];
    const float* emb_a = (const float*)d_in[3];
    const float* Wih_t = (const float*)d_in[4];
    const float* Whh_t = (const float*)d_in[5];
    const float* bih_t = (const float*)d_in[6];
    const float* bhh_t = (const float*)d_in[7];
    const float* Wih_a = (const float*)d_in[8];
    const float* Whh_a = (const float*)d_in[9];
    const float* bih_a = (const float*)d_in[10];
    const float* bhh_a = (const float*)d_in[11];
    const float* W1 = (const float*)d_in[12];
    const float* b1 = (const float*)d_in[13];
    const float* W2 = (const float*)d_in[14];
    const float* b2 = (const float*)d_in[15];
    const float* W3 = (const float*)d_in[16];
    const float* b3 = (const float*)d_in[17];

    // workspace layout (bytes):
    //   0      msg_t   2 x 2048 u64 = 32768
    //   32768  msg_a   2 x 2048 u64 = 32768
    //   65536  claim   8 u32 (hub election)
    //   65792  flags   8 XCD x 64 u32 (256B padded: no cross-L2 false sharing)
    //   67840  stage   8 XCD x 2 x 2048 f32 = 131072
    //   262144 gxt     128 x 8192 f32 = 4 MiB
    //   +4MiB  gxa     16 x 8192 f32 = 512 KiB
    u64* msg_t = (u64*)d_ws;
    u64* msg_a = (u64*)((char*)d_ws + 32768);
    unsigned* claim = (unsigned*)((char*)d_ws + 65536);
    unsigned* flags = (unsigned*)((char*)d_ws + 65792);
    float* stage = (float*)((char*)d_ws + 67840);
    float* gxt = (float*)((char*)d_ws + 262144);
    float* gxa = (float*)((char*)d_ws + 262144 + 4194304);

    // zero msg tags + claim + flags (stale values from a previous replay alias)
    hipMemsetAsync(d_ws, 0, 69888, stream);
    gates_x_gemm<32><<<dim3(128, 4), 256, 0, stream>>>(x_t, emb_t, Wih_t, bih_t,
                                                       bhh_t, gxt);
    gates_x_gemm<16><<<dim3(128, 1), 256, 0, stream>>>(x_a, emb_a, Wih_a, bih_a,
                                                       bhh_a, gxa);
    lstm_mlp_persistent<<<NB, 512, 0, stream>>>(Whh_t, Whh_a, gxt, gxa, W1, b1,
                                                W2, b2, W3, b3, msg_t, msg_a,
                                                claim, flags, stage,
                                                (float*)d_out);
}